// Round 14
// baseline (120.356 us; speedup 1.0000x reference)
//
#include <hip/hip_runtime.h>
#include <math.h>

#define BB 32
#define SS 4096
#define DD 1024
#define SEGS 16                        // segments per batch (longer streams won R11)
#define ROWS_PER_SEG (SS / SEGS)       // 256
#define G16 (ROWS_PER_SEG / 16)        // 16 groups of 16 rows (R14: halve barrier count)
#define NBLK2 (BB * SEGS)              // 512 blocks = exactly 2 per CU (grid caps residency)

typedef float vf4 __attribute__((ext_vector_type(4)));

__device__ __forceinline__ float dot4v(vf4 a, vf4 b) {
    return a.x * b.x + a.y * b.y + a.z * b.z + a.w * b.w;
}

// K1: dec_att[b,d] = sum_k dec[b,k] * Win[d,k]   (x @ W.T)
// 8 b's per butterfly group (4 groups) — halves the serial DS-chain count.
__global__ __launch_bounds__(256) void k1_decatt(const float* __restrict__ dec,
                                                 const float* __restrict__ Win,
                                                 float* __restrict__ dec_att) {
    const int wid = threadIdx.x >> 6, lane = threadIdx.x & 63;
    const int d = blockIdx.x * 4 + wid;          // 256 blocks -> 1024 d
    const vf4* Wrow = (const vf4*)(Win + (size_t)d * DD);
    vf4 w4[4];
    #pragma unroll
    for (int i = 0; i < 4; ++i) w4[i] = __builtin_nontemporal_load(&Wrow[lane + i * 64]);
    #pragma unroll 1
    for (int bg = 0; bg < 4; ++bg) {
        float p[8] = {0.f, 0.f, 0.f, 0.f, 0.f, 0.f, 0.f, 0.f};
        #pragma unroll
        for (int j = 0; j < 8; ++j) {
            const vf4* x = (const vf4*)(dec + (size_t)(bg * 8 + j) * DD);
            #pragma unroll
            for (int i = 0; i < 4; ++i) p[j] += dot4v(w4[i], x[lane + i * 64]);
        }
        #pragma unroll
        for (int off = 32; off > 0; off >>= 1) {
            #pragma unroll
            for (int j = 0; j < 8; ++j) p[j] += __shfl_xor(p[j], off, 64);
        }
        if (lane == 0) {
            #pragma unroll
            for (int j = 0; j < 8; ++j)
                dec_att[(size_t)(bg * 8 + j) * DD + d] = p[j];
        }
    }
}

// K2: single-pass online-softmax scan, block-column-split, NONTEMPORAL enc
// loads (no-allocate streaming path: 157.6 -> 127.5 us — do not remove).
// R14: 16-row groups (16 barriers instead of 32). The 512-block grid caps
// residency at 2 blocks/CU, so VGPRs up to 256 are FREE — waves_per_eu(2,2)
// pins the allocator to that budget (R10 lesson: without the pin, cold-code
// heuristics can squeeze to 56 VGPR and destroy the register double buffer).
__global__ __launch_bounds__(256) __attribute__((amdgpu_waves_per_eu(2, 2)))
void k2_scan(const float* __restrict__ enc,
             const float* __restrict__ dec_att,
             float* __restrict__ scores,
             float* __restrict__ pacc,
             float* __restrict__ pml) {
    const int tid = threadIdx.x;
    const int wid = tid >> 6, lane = tid & 63;
    const int b = blockIdx.x / SEGS, seg = blockIdx.x % SEGS;
    const int s0 = seg * ROWS_PER_SEG;

    const vf4* encc = (const vf4*)(enc + ((size_t)b * SS + s0) * DD) + tid;
    const vf4 q4 = ((const vf4*)(dec_att + (size_t)b * DD))[tid];
    float* scores_row = scores + (size_t)b * SS + s0;

    vf4 a4 = (vf4)(0.f);
    float m = -1e30f, l = 0.f;

    __shared__ __align__(16) float lds_p[2][16][4];   // [buf][row][wave]

    vf4 eC[16], eN[16];
    #pragma unroll
    for (int j = 0; j < 16; ++j)
        eC[j] = __builtin_nontemporal_load(&encc[(size_t)j * (DD / 4)]);

    auto process = [&](int g, const vf4* e) {
        float p[16];
        #pragma unroll
        for (int j = 0; j < 16; ++j) p[j] = dot4v(q4, e[j]);
        // 16 interleaved 64-lane butterflies
        #pragma unroll
        for (int off = 32; off > 0; off >>= 1) {
            #pragma unroll
            for (int j = 0; j < 16; ++j) p[j] += __shfl_xor(p[j], off, 64);
        }
        if (lane == 0) {
            #pragma unroll
            for (int j = 0; j < 16; ++j) lds_p[g & 1][j][wid] = p[j];
        }
        // LDS-visibility only; do NOT drain vmcnt (prefetch stays in flight)
        asm volatile("s_waitcnt lgkmcnt(0)" ::: "memory");
        __builtin_amdgcn_s_barrier();
        float s[16];
        #pragma unroll
        for (int j = 0; j < 16; ++j) {
            const vf4 v = *(const vf4*)&lds_p[g & 1][j][0];
            s[j] = (v.x + v.y) + (v.z + v.w);
        }
        if (tid == 0) {
            #pragma unroll
            for (int j = 0; j < 16; ++j) scores_row[g * 16 + j] = s[j];
        }
        float mp = s[0];
        #pragma unroll
        for (int j = 1; j < 16; ++j) mp = fmaxf(mp, s[j]);
        const float mn = fmaxf(m, mp);
        const float sc = __expf(m - mn);
        float w[16], lsum = 0.f;
        #pragma unroll
        for (int j = 0; j < 16; ++j) { w[j] = __expf(s[j] - mn); lsum += w[j]; }
        l = l * sc + lsum;
        a4 *= sc;
        #pragma unroll
        for (int j = 0; j < 16; ++j) a4 += w[j] * e[j];
        m = mn;
    };

    #pragma unroll 1
    for (int g = 0; g < G16 - 1; ++g) {
        // prefetch next group before this group's reduce fence
        #pragma unroll
        for (int j = 0; j < 16; ++j)
            eN[j] = __builtin_nontemporal_load(&encc[(size_t)((g + 1) * 16 + j) * (DD / 4)]);
        process(g, eC);
        #pragma unroll
        for (int j = 0; j < 16; ++j) eC[j] = eN[j];
    }
    process(G16 - 1, eC);

    // epilogue: per-thread columns -> direct coalesced partial write
    ((vf4*)(pacc + (size_t)blockIdx.x * DD))[tid] = a4;
    if (tid == 0) {
        pml[(size_t)blockIdx.x * 2 + 0] = m;
        pml[(size_t)blockIdx.x * 2 + 1] = l;
    }
}

// K3 (fused with old K4): combine seg partials -> weighted[b,:]; then
// normalize this block's slice of raw scores in place. 128 blocks x 64 thr.
__global__ __launch_bounds__(64) void k3_combine(const float* __restrict__ pacc,
                                                 const float* __restrict__ pml,
                                                 float* __restrict__ weighted,
                                                 float* __restrict__ wts) {
    const int b = blockIdx.x >> 2, qtr = blockIdx.x & 3;
    const int col = qtr * 64 + threadIdx.x;   // float4 column 0..255
    float mg = -1e30f;
    #pragma unroll 8
    for (int c = 0; c < SEGS; ++c) mg = fmaxf(mg, pml[(size_t)(b * SEGS + c) * 2]);
    float lg = 0.f;
    #pragma unroll 8
    for (int c = 0; c < SEGS; ++c)
        lg += pml[(size_t)(b * SEGS + c) * 2 + 1] * __expf(pml[(size_t)(b * SEGS + c) * 2] - mg);
    vf4 acc = (vf4)(0.f);
    #pragma unroll 4
    for (int c = 0; c < SEGS; ++c) {
        const float f = __expf(pml[(size_t)(b * SEGS + c) * 2] - mg);
        const vf4 v = __builtin_nontemporal_load(
            &((const vf4*)(pacc + (size_t)(b * SEGS + c) * DD))[col]);
        acc += f * v;
    }
    const float inv = 1.f / lg;
    ((vf4*)(weighted + (size_t)b * DD))[col] = acc * inv;

    // fused score normalization: this block owns wts[b, qtr*1024 .. +1024)
    vf4* wq = (vf4*)(wts + (size_t)b * SS + qtr * (SS / 4));
    #pragma unroll
    for (int i = 0; i < 4; ++i) {
        vf4 v = wq[threadIdx.x + i * 64];
        v.x = __expf(v.x - mg) * inv;
        v.y = __expf(v.y - mg) * inv;
        v.z = __expf(v.z - mg) * inv;
        v.w = __expf(v.w - mg) * inv;
        wq[threadIdx.x + i * 64] = v;
    }
}

// K5: out[b,d] = tanh( [weighted, dec] . Wout[d,:] ), Wout row-major [D, 2D].
// 8 b's per butterfly group (4 groups) — halves the serial DS-chain count.
__global__ __launch_bounds__(256) void k5_out(const float* __restrict__ weighted,
                                              const float* __restrict__ dec,
                                              const float* __restrict__ Wout,
                                              float* __restrict__ out) {
    const int wid = threadIdx.x >> 6, lane = threadIdx.x & 63;
    const int d = blockIdx.x * 4 + wid;  // 256 blocks -> 1024 d
    const vf4* Wrow = (const vf4*)(Wout + (size_t)d * (2 * DD));
    vf4 w4[8];
    #pragma unroll
    for (int i = 0; i < 8; ++i) w4[i] = __builtin_nontemporal_load(&Wrow[lane + i * 64]);
    #pragma unroll 1
    for (int bg = 0; bg < 4; ++bg) {
        float p[8] = {0.f, 0.f, 0.f, 0.f, 0.f, 0.f, 0.f, 0.f};
        #pragma unroll
        for (int j = 0; j < 8; ++j) {
            const int b = bg * 8 + j;
            const vf4* xw = (const vf4*)(weighted + (size_t)b * DD);
            const vf4* xd = (const vf4*)(dec + (size_t)b * DD);
            #pragma unroll
            for (int i = 0; i < 4; ++i) {
                p[j] += dot4v(w4[i], xw[lane + i * 64]);
                p[j] += dot4v(w4[i + 4], xd[lane + i * 64]);
            }
        }
        #pragma unroll
        for (int off = 32; off > 0; off >>= 1) {
            #pragma unroll
            for (int j = 0; j < 8; ++j) p[j] += __shfl_xor(p[j], off, 64);
        }
        if (lane == 0) {
            #pragma unroll
            for (int j = 0; j < 8; ++j)
                out[(size_t)(bg * 8 + j) * DD + d] = tanhf(p[j]);
        }
    }
}

extern "C" void kernel_launch(void* const* d_in, const int* in_sizes, int n_in,
                              void* d_out, int out_size, void* d_ws, size_t ws_size,
                              hipStream_t stream) {
    (void)in_sizes; (void)n_in; (void)out_size; (void)ws_size;
    const float* dec  = (const float*)d_in[0];   // [B, D]
    const float* enc  = (const float*)d_in[1];   // [B, S, D]
    const float* Win  = (const float*)d_in[2];   // [D, D]
    const float* Wout = (const float*)d_in[3];   // [D, 2D]

    float* out_final = (float*)d_out;                // [B, D]
    float* out_wts   = out_final + (size_t)BB * DD;  // [B, S]

    // workspace layout (floats)
    float* ws       = (float*)d_ws;
    float* dec_att  = ws;                                 // B*D
    float* pacc     = dec_att + (size_t)BB * DD;          // NBLK2*D
    float* pml      = pacc + (size_t)NBLK2 * DD;          // NBLK2*2
    float* weighted = pml + (size_t)NBLK2 * 2;            // B*D

    hipLaunchKernelGGL(k1_decatt, dim3(DD / 4), dim3(256), 0, stream, dec, Win, dec_att);
    hipLaunchKernelGGL(k2_scan, dim3(NBLK2), dim3(256), 0, stream, enc, dec_att, out_wts, pacc, pml);
    hipLaunchKernelGGL(k3_combine, dim3(BB * 4), dim3(64), 0, stream, pacc, pml, weighted, out_wts);
    hipLaunchKernelGGL(k5_out, dim3(DD / 4), dim3(256), 0, stream, weighted, dec, Wout, out_final);
}

// Round 15
// 117.259 us; speedup vs baseline: 1.0264x; 1.0264x over previous
//
#include <hip/hip_runtime.h>
#include <math.h>

#define BB 32
#define SS 4096
#define DD 1024
#define SEGS 16                        // segments per batch (longer streams won R11)
#define ROWS_PER_SEG (SS / SEGS)       // 256
#define GROUPS (ROWS_PER_SEG / 8)      // 32 groups of 8 rows
#define NBLK2 (BB * SEGS)              // 512 blocks = exactly 2 per CU

typedef float vf4 __attribute__((ext_vector_type(4)));

__device__ __forceinline__ float dot4v(vf4 a, vf4 b) {
    return a.x * b.x + a.y * b.y + a.z * b.z + a.w * b.w;
}

// K1: dec_att[b,d] = sum_k dec[b,k] * Win[d,k]   (x @ W.T)
// 8 b's per butterfly group (4 groups) — halves the serial DS-chain count.
__global__ __launch_bounds__(256) void k1_decatt(const float* __restrict__ dec,
                                                 const float* __restrict__ Win,
                                                 float* __restrict__ dec_att) {
    const int wid = threadIdx.x >> 6, lane = threadIdx.x & 63;
    const int d = blockIdx.x * 4 + wid;          // 256 blocks -> 1024 d
    const vf4* Wrow = (const vf4*)(Win + (size_t)d * DD);
    vf4 w4[4];
    #pragma unroll
    for (int i = 0; i < 4; ++i) w4[i] = __builtin_nontemporal_load(&Wrow[lane + i * 64]);
    #pragma unroll 1
    for (int bg = 0; bg < 4; ++bg) {
        float p[8] = {0.f, 0.f, 0.f, 0.f, 0.f, 0.f, 0.f, 0.f};
        #pragma unroll
        for (int j = 0; j < 8; ++j) {
            const vf4* x = (const vf4*)(dec + (size_t)(bg * 8 + j) * DD);
            #pragma unroll
            for (int i = 0; i < 4; ++i) p[j] += dot4v(w4[i], x[lane + i * 64]);
        }
        #pragma unroll
        for (int off = 32; off > 0; off >>= 1) {
            #pragma unroll
            for (int j = 0; j < 8; ++j) p[j] += __shfl_xor(p[j], off, 64);
        }
        if (lane == 0) {
            #pragma unroll
            for (int j = 0; j < 8; ++j)
                dec_att[(size_t)(bg * 8 + j) * DD + d] = p[j];
        }
    }
}

// K2: single-pass online-softmax scan, block-column-split, NONTEMPORAL enc
// loads (no-allocate streaming path: 157.6 -> 127.5 us — do not remove).
// NOTE (R10 lesson): do NOT add cold epilogue code here — it re-budgets the
// register allocator (56 VGPR schedule) and destroys the 8-row double buffer.
// NOTE (R14 lesson): 16-row groups + waves_per_eu(2,2) pin regressed (+2.5us);
// 8-row groups with default allocator is the local optimum.
// BYTE-IDENTICAL to R12's winner (117.8 us).
__global__ __launch_bounds__(256) void k2_scan(const float* __restrict__ enc,
                                               const float* __restrict__ dec_att,
                                               float* __restrict__ scores,
                                               float* __restrict__ pacc,
                                               float* __restrict__ pml) {
    const int tid = threadIdx.x;
    const int wid = tid >> 6, lane = tid & 63;
    const int b = blockIdx.x / SEGS, seg = blockIdx.x % SEGS;
    const int s0 = seg * ROWS_PER_SEG;

    const vf4* encc = (const vf4*)(enc + ((size_t)b * SS + s0) * DD) + tid;
    const vf4 q4 = ((const vf4*)(dec_att + (size_t)b * DD))[tid];
    float* scores_row = scores + (size_t)b * SS + s0;

    vf4 a4 = (vf4)(0.f);
    float m = -1e30f, l = 0.f;

    __shared__ __align__(16) float lds_p[2][8][4];   // [buf][row][wave]

    vf4 eC[8], eN[8];
    #pragma unroll
    for (int j = 0; j < 8; ++j)
        eC[j] = __builtin_nontemporal_load(&encc[(size_t)j * (DD / 4)]);

    auto process = [&](int g, const vf4* e) {
        float p[8];
        #pragma unroll
        for (int j = 0; j < 8; ++j) p[j] = dot4v(q4, e[j]);
        // 8 interleaved 64-lane butterflies
        #pragma unroll
        for (int off = 32; off > 0; off >>= 1) {
            #pragma unroll
            for (int j = 0; j < 8; ++j) p[j] += __shfl_xor(p[j], off, 64);
        }
        if (lane == 0) {
            #pragma unroll
            for (int j = 0; j < 8; ++j) lds_p[g & 1][j][wid] = p[j];
        }
        // LDS-visibility only; do NOT drain vmcnt (prefetch stays in flight)
        asm volatile("s_waitcnt lgkmcnt(0)" ::: "memory");
        __builtin_amdgcn_s_barrier();
        float s[8];
        #pragma unroll
        for (int j = 0; j < 8; ++j) {
            const vf4 v = *(const vf4*)&lds_p[g & 1][j][0];
            s[j] = (v.x + v.y) + (v.z + v.w);
        }
        if (tid == 0) {
            #pragma unroll
            for (int j = 0; j < 8; ++j) scores_row[g * 8 + j] = s[j];
        }
        float mp = s[0];
        #pragma unroll
        for (int j = 1; j < 8; ++j) mp = fmaxf(mp, s[j]);
        const float mn = fmaxf(m, mp);
        const float sc = __expf(m - mn);
        float w[8], lsum = 0.f;
        #pragma unroll
        for (int j = 0; j < 8; ++j) { w[j] = __expf(s[j] - mn); lsum += w[j]; }
        l = l * sc + lsum;
        a4 *= sc;
        #pragma unroll
        for (int j = 0; j < 8; ++j) a4 += w[j] * e[j];
        m = mn;
    };

    #pragma unroll 1
    for (int g = 0; g < GROUPS - 1; ++g) {
        // prefetch next group before this group's reduce fence
        #pragma unroll
        for (int j = 0; j < 8; ++j)
            eN[j] = __builtin_nontemporal_load(&encc[(size_t)((g + 1) * 8 + j) * (DD / 4)]);
        process(g, eC);
        #pragma unroll
        for (int j = 0; j < 8; ++j) eC[j] = eN[j];
    }
    process(GROUPS - 1, eC);

    // epilogue: per-thread columns -> direct coalesced partial write
    ((vf4*)(pacc + (size_t)blockIdx.x * DD))[tid] = a4;
    if (tid == 0) {
        pml[(size_t)blockIdx.x * 2 + 0] = m;
        pml[(size_t)blockIdx.x * 2 + 1] = l;
    }
}

// K3 (fused with old K4): combine seg partials -> weighted[b,:]; then
// normalize this block's slice of raw scores in place. 128 blocks x 64 thr.
__global__ __launch_bounds__(64) void k3_combine(const float* __restrict__ pacc,
                                                 const float* __restrict__ pml,
                                                 float* __restrict__ weighted,
                                                 float* __restrict__ wts) {
    const int b = blockIdx.x >> 2, qtr = blockIdx.x & 3;
    const int col = qtr * 64 + threadIdx.x;   // float4 column 0..255
    float mg = -1e30f;
    #pragma unroll 8
    for (int c = 0; c < SEGS; ++c) mg = fmaxf(mg, pml[(size_t)(b * SEGS + c) * 2]);
    float lg = 0.f;
    #pragma unroll 8
    for (int c = 0; c < SEGS; ++c)
        lg += pml[(size_t)(b * SEGS + c) * 2 + 1] * __expf(pml[(size_t)(b * SEGS + c) * 2] - mg);
    vf4 acc = (vf4)(0.f);
    #pragma unroll 4
    for (int c = 0; c < SEGS; ++c) {
        const float f = __expf(pml[(size_t)(b * SEGS + c) * 2] - mg);
        const vf4 v = __builtin_nontemporal_load(
            &((const vf4*)(pacc + (size_t)(b * SEGS + c) * DD))[col]);
        acc += f * v;
    }
    const float inv = 1.f / lg;
    ((vf4*)(weighted + (size_t)b * DD))[col] = acc * inv;

    // fused score normalization: this block owns wts[b, qtr*1024 .. +1024)
    vf4* wq = (vf4*)(wts + (size_t)b * SS + qtr * (SS / 4));
    #pragma unroll
    for (int i = 0; i < 4; ++i) {
        vf4 v = wq[threadIdx.x + i * 64];
        v.x = __expf(v.x - mg) * inv;
        v.y = __expf(v.y - mg) * inv;
        v.z = __expf(v.z - mg) * inv;
        v.w = __expf(v.w - mg) * inv;
        wq[threadIdx.x + i * 64] = v;
    }
}

// K5: out[b,d] = tanh( [weighted, dec] . Wout[d,:] ), Wout row-major [D, 2D].
// 8 b's per butterfly group (4 groups) — halves the serial DS-chain count.
__global__ __launch_bounds__(256) void k5_out(const float* __restrict__ weighted,
                                              const float* __restrict__ dec,
                                              const float* __restrict__ Wout,
                                              float* __restrict__ out) {
    const int wid = threadIdx.x >> 6, lane = threadIdx.x & 63;
    const int d = blockIdx.x * 4 + wid;  // 256 blocks -> 1024 d
    const vf4* Wrow = (const vf4*)(Wout + (size_t)d * (2 * DD));
    vf4 w4[8];
    #pragma unroll
    for (int i = 0; i < 8; ++i) w4[i] = __builtin_nontemporal_load(&Wrow[lane + i * 64]);
    #pragma unroll 1
    for (int bg = 0; bg < 4; ++bg) {
        float p[8] = {0.f, 0.f, 0.f, 0.f, 0.f, 0.f, 0.f, 0.f};
        #pragma unroll
        for (int j = 0; j < 8; ++j) {
            const int b = bg * 8 + j;
            const vf4* xw = (const vf4*)(weighted + (size_t)b * DD);
            const vf4* xd = (const vf4*)(dec + (size_t)b * DD);
            #pragma unroll
            for (int i = 0; i < 4; ++i) {
                p[j] += dot4v(w4[i], xw[lane + i * 64]);
                p[j] += dot4v(w4[i + 4], xd[lane + i * 64]);
            }
        }
        #pragma unroll
        for (int off = 32; off > 0; off >>= 1) {
            #pragma unroll
            for (int j = 0; j < 8; ++j) p[j] += __shfl_xor(p[j], off, 64);
        }
        if (lane == 0) {
            #pragma unroll
            for (int j = 0; j < 8; ++j)
                out[(size_t)(bg * 8 + j) * DD + d] = tanhf(p[j]);
        }
    }
}

extern "C" void kernel_launch(void* const* d_in, const int* in_sizes, int n_in,
                              void* d_out, int out_size, void* d_ws, size_t ws_size,
                              hipStream_t stream) {
    (void)in_sizes; (void)n_in; (void)out_size; (void)ws_size;
    const float* dec  = (const float*)d_in[0];   // [B, D]
    const float* enc  = (const float*)d_in[1];   // [B, S, D]
    const float* Win  = (const float*)d_in[2];   // [D, D]
    const float* Wout = (const float*)d_in[3];   // [D, 2D]

    float* out_final = (float*)d_out;                // [B, D]
    float* out_wts   = out_final + (size_t)BB * DD;  // [B, S]

    // workspace layout (floats)
    float* ws       = (float*)d_ws;
    float* dec_att  = ws;                                 // B*D
    float* pacc     = dec_att + (size_t)BB * DD;          // NBLK2*D
    float* pml      = pacc + (size_t)NBLK2 * DD;          // NBLK2*2
    float* weighted = pml + (size_t)NBLK2 * 2;            // B*D

    hipLaunchKernelGGL(k1_decatt, dim3(DD / 4), dim3(256), 0, stream, dec, Win, dec_att);
    hipLaunchKernelGGL(k2_scan, dim3(NBLK2), dim3(256), 0, stream, enc, dec_att, out_wts, pacc, pml);
    hipLaunchKernelGGL(k3_combine, dim3(BB * 4), dim3(64), 0, stream, pacc, pml, weighted, out_wts);
    hipLaunchKernelGGL(k5_out, dim3(DD / 4), dim3(256), 0, stream, weighted, dec, Wout, out_final);
}